// Round 1
// baseline (132.451 us; speedup 1.0000x reference)
//
#include <hip/hip_runtime.h>
#include <math.h>

#define NQ 8
#define NDEPTH 3
#define FEAT 512
#define NCLS 10
#define NBATCH 8192
#define NGATES (NDEPTH * NQ * 3) // 72

// ---------------------------------------------------------------------------
// Kernel 1: precompute (cos(theta/2), sin(theta/2)) for the 72 circuit gates.
// Must run every launch: d_ws is re-poisoned before each timed call.
// ---------------------------------------------------------------------------
__global__ void gate_precompute(const float* __restrict__ qnn_w,
                                float* __restrict__ gates) {
    int i = blockIdx.x * blockDim.x + threadIdx.x;
    if (i < NGATES) {
        float th = 0.5f * qnn_w[i];
        gates[2 * i]     = cosf(th);
        gates[2 * i + 1] = sinf(th);
    }
}

// ---------------------------------------------------------------------------
// State layout: flat amplitude index s (bit q of s = qubit q), s = lane*4 + j.
//   j (bits 0..1): in-register index 0..3
//   lane (bits 2..7): wave lane
// re[j], im[j] hold amplitude (lane*4 + j).
// ---------------------------------------------------------------------------

// RY on qubit 0 (pairs j=(0,1),(2,3)): new0=c*a0-s*a1, new1=s*a0+c*a1 (real)
__device__ __forceinline__ void ry_b0(float c, float s, float (&re)[4], float (&im)[4]) {
    float t0, t1;
    t0 = c * re[0] - s * re[1]; t1 = s * re[0] + c * re[1]; re[0] = t0; re[1] = t1;
    t0 = c * im[0] - s * im[1]; t1 = s * im[0] + c * im[1]; im[0] = t0; im[1] = t1;
    t0 = c * re[2] - s * re[3]; t1 = s * re[2] + c * re[3]; re[2] = t0; re[3] = t1;
    t0 = c * im[2] - s * im[3]; t1 = s * im[2] + c * im[3]; im[2] = t0; im[3] = t1;
}

// RY on qubit 1 (pairs j=(0,2),(1,3))
__device__ __forceinline__ void ry_b1(float c, float s, float (&re)[4], float (&im)[4]) {
    float t0, t1;
    t0 = c * re[0] - s * re[2]; t1 = s * re[0] + c * re[2]; re[0] = t0; re[2] = t1;
    t0 = c * im[0] - s * im[2]; t1 = s * im[0] + c * im[2]; im[0] = t0; im[2] = t1;
    t0 = c * re[1] - s * re[3]; t1 = s * re[1] + c * re[3]; re[1] = t0; re[3] = t1;
    t0 = c * im[1] - s * im[3]; t1 = s * im[1] + c * im[3]; im[1] = t0; im[3] = t1;
}

// RX on qubit 0 (pairs j=(0,1),(2,3)): new = c*a - i*s*partner (symmetric)
__device__ __forceinline__ void rx_b0(float c, float s, float (&re)[4], float (&im)[4]) {
    float r0, i0, r1, i1;
    r0 = fmaf(c, re[0],  s * im[1]); i0 = fmaf(c, im[0], -s * re[1]);
    r1 = fmaf(c, re[1],  s * im[0]); i1 = fmaf(c, im[1], -s * re[0]);
    re[0] = r0; im[0] = i0; re[1] = r1; im[1] = i1;
    r0 = fmaf(c, re[2],  s * im[3]); i0 = fmaf(c, im[2], -s * re[3]);
    r1 = fmaf(c, re[3],  s * im[2]); i1 = fmaf(c, im[3], -s * re[2]);
    re[2] = r0; im[2] = i0; re[3] = r1; im[3] = i1;
}

// RX on qubit 1 (pairs j=(0,2),(1,3))
__device__ __forceinline__ void rx_b1(float c, float s, float (&re)[4], float (&im)[4]) {
    float r0, i0, r1, i1;
    r0 = fmaf(c, re[0],  s * im[2]); i0 = fmaf(c, im[0], -s * re[2]);
    r1 = fmaf(c, re[2],  s * im[0]); i1 = fmaf(c, im[2], -s * re[0]);
    re[0] = r0; im[0] = i0; re[2] = r1; im[2] = i1;
    r0 = fmaf(c, re[1],  s * im[3]); i0 = fmaf(c, im[1], -s * re[3]);
    r1 = fmaf(c, re[3],  s * im[1]); i1 = fmaf(c, im[3], -s * re[1]);
    re[1] = r0; im[1] = i0; re[3] = r1; im[3] = i1;
}

// RX on qubit q>=2: cross-lane, mask = 1<<(q-2). new = c*a - i*s*partner
__device__ __forceinline__ void rx_x(float c, float s, int mask,
                                     float (&re)[4], float (&im)[4]) {
#pragma unroll
    for (int j = 0; j < 4; j++) {
        float pr = __shfl_xor(re[j], mask);
        float pi = __shfl_xor(im[j], mask);
        re[j] = fmaf(c, re[j],  s * pi);
        im[j] = fmaf(c, im[j], -s * pr);
    }
}

// RY on qubit q>=2: cross-lane. bit=my qubit-q bit. new = c*a + (bit? s : -s)*partner
__device__ __forceinline__ void ry_x(float c, float s, int mask, int bit,
                                     float (&re)[4], float (&im)[4]) {
    float se = bit ? s : -s;
#pragma unroll
    for (int j = 0; j < 4; j++) {
        float pr = __shfl_xor(re[j], mask);
        float pi = __shfl_xor(im[j], mask);
        re[j] = fmaf(c, re[j], se * pr);
        im[j] = fmaf(c, im[j], se * pi);
    }
}

__global__ __launch_bounds__(256) void qsim_kernel(
        const float* __restrict__ x, const float* __restrict__ proj_w,
        const float* __restrict__ gates_g, const float* __restrict__ out_w,
        const float* __restrict__ out_b, float* __restrict__ out) {
    __shared__ float gl[NGATES * 2]; // (c,s) per gate, order (l,q,r)

    int tid = threadIdx.x;
    if (tid < NGATES * 2) gl[tid] = gates_g[tid];
    __syncthreads();

    int lane = tid & 63;
    int wave = tid >> 6;
    int b = blockIdx.x * 4 + wave;
    if (b >= NBATCH) return;

    // ---- encoding angles: angles[q] = tanh(x[b]·proj_w[q]) * pi/2 ----------
    const float* xr = x + (size_t)b * FEAT;
    float xv[8];
#pragma unroll
    for (int k = 0; k < 8; k++) xv[k] = xr[lane + 64 * k];

    float d[8];
#pragma unroll
    for (int q = 0; q < 8; q++) {
        const float* pw = proj_w + q * FEAT;
        float acc = 0.f;
#pragma unroll
        for (int k = 0; k < 8; k++) acc = fmaf(xv[k], pw[lane + 64 * k], acc);
        d[q] = acc;
    }
    // butterfly reduce each of the 8 partial dots across the wave
#pragma unroll
    for (int q = 0; q < 8; q++) {
        float v = d[q];
#pragma unroll
        for (int off = 1; off < 64; off <<= 1) v += __shfl_xor(v, off);
        d[q] = v;
    }
    // Lane group g = lane>>3 computes cos/sin of half-angle for qubit g.
    int qsel = lane >> 3;
    float s0 = (qsel & 4) ? d[4] : d[0];
    float s1 = (qsel & 4) ? d[5] : d[1];
    float s2 = (qsel & 4) ? d[6] : d[2];
    float s3 = (qsel & 4) ? d[7] : d[3];
    float t0s = (qsel & 2) ? s2 : s0;
    float t1s = (qsel & 2) ? s3 : s1;
    float dq = (qsel & 1) ? t1s : t0s;
    float th_half = tanhf(dq) * 0.78539816339744830962f; // (pi/2)/2 * tanh
    float se_enc, ce_enc;
    sincosf(th_half, &se_enc, &ce_enc);

    // ---- init |0...0> ------------------------------------------------------
    float re[4] = {0.f, 0.f, 0.f, 0.f};
    float im[4] = {0.f, 0.f, 0.f, 0.f};
    if (lane == 0) re[0] = 1.f;

    // ---- RY encoding layer -------------------------------------------------
#pragma unroll
    for (int q = 0; q < NQ; q++) {
        float c = __shfl(ce_enc, q * 8);
        float s = __shfl(se_enc, q * 8);
        if (q == 0)      ry_b0(c, s, re, im);
        else if (q == 1) ry_b1(c, s, re, im);
        else             ry_x(c, s, 1 << (q - 2), (lane >> (q - 2)) & 1, re, im);
    }

    // ---- variational layers ------------------------------------------------
    for (int l = 0; l < NDEPTH; l++) {
        const float* g = &gl[l * NQ * 3 * 2];
#pragma unroll
        for (int q = 0; q < NQ; q++) {
            float c0 = g[q * 6 + 0], sv0 = g[q * 6 + 1];
            float c1 = g[q * 6 + 2], sv1 = g[q * 6 + 3];
            float c2 = g[q * 6 + 4], sv2 = g[q * 6 + 5];
            if (q == 0) {
                rx_b0(c0, sv0, re, im); ry_b0(c1, sv1, re, im); rx_b0(c2, sv2, re, im);
            } else if (q == 1) {
                rx_b1(c0, sv0, re, im); ry_b1(c1, sv1, re, im); rx_b1(c2, sv2, re, im);
            } else {
                int m = 1 << (q - 2);
                int bit = (lane >> (q - 2)) & 1;
                rx_x(c0, sv0, m, re, im);
                ry_x(c1, sv1, m, bit, re, im);
                rx_x(c2, sv2, m, re, im);
            }
        }
        // CNOT(0,1): control j-bit0, target j-bit1 -> swap amp1 <-> amp3
        { float t; t = re[1]; re[1] = re[3]; re[3] = t;
                   t = im[1]; im[1] = im[3]; im[3] = t; }
        // CNOT(1,2): control j-bit1, target lane-bit0 -> swap j=2,3 across lane^1
        re[2] = __shfl_xor(re[2], 1); im[2] = __shfl_xor(im[2], 1);
        re[3] = __shfl_xor(re[3], 1); im[3] = __shfl_xor(im[3], 1);
        // CNOT(q,q+1) for q=2..6: control lane-bit(q-2), target lane-bit(q-1)
#pragma unroll
        for (int q = 2; q < 7; q++) {
            int m = 1 << (q - 1);
            int bit = (lane >> (q - 2)) & 1;
#pragma unroll
            for (int j = 0; j < 4; j++) {
                float pr = __shfl_xor(re[j], m);
                float pi = __shfl_xor(im[j], m);
                re[j] = bit ? pr : re[j];
                im[j] = bit ? pi : im[j];
            }
        }
        // CNOT(7,0): control lane-bit5, target j-bit0 -> swap (0,1),(2,3) in-lane
        {
            int bit = (lane >> 5) & 1;
            float a0 = bit ? re[1] : re[0], a1 = bit ? re[0] : re[1];
            float a2 = bit ? re[3] : re[2], a3 = bit ? re[2] : re[3];
            re[0] = a0; re[1] = a1; re[2] = a2; re[3] = a3;
            a0 = bit ? im[1] : im[0]; a1 = bit ? im[0] : im[1];
            a2 = bit ? im[3] : im[2]; a3 = bit ? im[2] : im[3];
            im[0] = a0; im[1] = a1; im[2] = a2; im[3] = a3;
        }
    }

    // ---- PauliZ expectations ----------------------------------------------
    float p0 = re[0] * re[0] + im[0] * im[0];
    float p1 = re[1] * re[1] + im[1] * im[1];
    float p2 = re[2] * re[2] + im[2] * im[2];
    float p3 = re[3] * re[3] + im[3] * im[3];
    float pt = p0 + p1 + p2 + p3;
    float e[8];
    e[0] = p0 - p1 + p2 - p3; // sign by j-bit0
    e[1] = p0 + p1 - p2 - p3; // sign by j-bit1
#pragma unroll
    for (int q = 2; q < 8; q++) e[q] = ((lane >> (q - 2)) & 1) ? -pt : pt;
#pragma unroll
    for (int q = 0; q < 8; q++) {
        float v = e[q];
#pragma unroll
        for (int off = 1; off < 64; off <<= 1) v += __shfl_xor(v, off);
        e[q] = v;
    }

    // ---- output head: out[b,c] = sum_q e[q]*out_w[c,q] + out_b[c] ----------
    if (lane < NCLS) {
        const float* wrow = out_w + lane * NQ;
        float acc = out_b[lane];
#pragma unroll
        for (int q = 0; q < 8; q++) acc = fmaf(e[q], wrow[q], acc);
        out[(size_t)b * NCLS + lane] = acc;
    }
}

extern "C" void kernel_launch(void* const* d_in, const int* in_sizes, int n_in,
                              void* d_out, int out_size, void* d_ws, size_t ws_size,
                              hipStream_t stream) {
    const float* x      = (const float*)d_in[0];
    const float* proj_w = (const float*)d_in[1];
    const float* qnn_w  = (const float*)d_in[2];
    const float* out_w  = (const float*)d_in[3];
    const float* out_b  = (const float*)d_in[4];
    float* out   = (float*)d_out;
    float* gates = (float*)d_ws; // 72 * 2 floats = 576 B

    gate_precompute<<<1, 128, 0, stream>>>(qnn_w, gates);
    qsim_kernel<<<NBATCH / 4, 256, 0, stream>>>(x, proj_w, gates, out_w, out_b, out);
}

// Round 2
// 85.562 us; speedup vs baseline: 1.5480x; 1.5480x over previous
//
#include <hip/hip_runtime.h>
#include <math.h>

#define NQ 8
#define NDEPTH 3
#define FEAT 512
#define NCLS 10
#define NBATCH 8192

// ---------------------------------------------------------------------------
// Kernel 1: fuse RX(t2)*RY(t1)*RX(t0) per (layer,qubit) into one complex 2x2.
// Layout: gates[(l*NQ+q)*8] = {U00r,U00i,U01r,U01i,U10r,U10i,U11r,U11i}
// Runs every launch (d_ws re-poisoned each call).
// ---------------------------------------------------------------------------
__global__ void gate_precompute(const float* __restrict__ qnn_w,
                                float* __restrict__ gates) {
    int i = threadIdx.x; // gate index l*NQ+q
    if (i < NDEPTH * NQ) {
        float t0 = 0.5f * qnn_w[i * 3 + 0];
        float t1 = 0.5f * qnn_w[i * 3 + 1];
        float t2 = 0.5f * qnn_w[i * 3 + 2];
        float c0 = cosf(t0), s0 = sinf(t0);
        float c1 = cosf(t1), s1 = sinf(t1);
        float c2 = cosf(t2), s2 = sinf(t2);
        // M1 = RY(t1)*RX(t0)
        float m00r =  c1 * c0, m00i =  s1 * s0;
        float m01r = -s1 * c0, m01i = -c1 * s0;
        float m10r =  s1 * c0, m10i = -c1 * s0;
        float m11r =  c1 * c0, m11i = -s1 * s0;
        // U = RX(t2)*M1;  (-i*s2)*(a+bi) = s2*b - i*s2*a
        float* g = gates + i * 8;
        g[0] =  c2 * m00r + s2 * m10i;  g[1] =  c2 * m00i - s2 * m10r; // U00
        g[2] =  c2 * m01r + s2 * m11i;  g[3] =  c2 * m01i - s2 * m11r; // U01
        g[4] =  s2 * m00i + c2 * m10r;  g[5] = -s2 * m00r + c2 * m10i; // U10
        g[6] =  s2 * m01i + c2 * m11r;  g[7] = -s2 * m01r + c2 * m11i; // U11
    }
}

// ---------------------------------------------------------------------------
// DPP helpers (VALU cross-lane, zero DS-pipe cost)
// ---------------------------------------------------------------------------
template <int CTRL, int ROW_MASK>
__device__ __forceinline__ float dpp_term(float v) {
    return __int_as_float(__builtin_amdgcn_update_dpp(
        0, __float_as_int(v), CTRL, ROW_MASK, 0xf, true));
}

// full 64-lane sum, result broadcast to all lanes (classic row_shr/bcast ladder)
__device__ __forceinline__ float wave_sum_bcast(float v) {
    v += dpp_term<0x111, 0xf>(v); // row_shr:1
    v += dpp_term<0x112, 0xf>(v); // row_shr:2
    v += dpp_term<0x114, 0xf>(v); // row_shr:4
    v += dpp_term<0x118, 0xf>(v); // row_shr:8  -> lane15 of each row = row sum
    v += dpp_term<0x142, 0xa>(v); // row_bcast15 into rows 1,3
    v += dpp_term<0x143, 0xc>(v); // row_bcast31 into rows 2,3 -> lane63 = total
    return __int_as_float(__builtin_amdgcn_readlane(__float_as_int(v), 63));
}

__device__ __forceinline__ float bcastlane(float v, int srclane) {
    return __int_as_float(__builtin_amdgcn_readlane(__float_as_int(v), srclane));
}

// quad_perm xor1 = [1,0,3,2] -> 0xB1 ; xor2 = [2,3,0,1] -> 0x4E
template <int CTRL>
__device__ __forceinline__ float dpp_xor(float v) {
    return __int_as_float(__builtin_amdgcn_update_dpp(
        0, __float_as_int(v), CTRL, 0xf, 0xf, true));
}

__device__ __forceinline__ float fast_tanh(float v) {
    float e = __expf(2.f * v);
    return 1.f - 2.f / (e + 1.f);
}

// ---------------------------------------------------------------------------
// General complex 2x2 gate application
// State layout: amp index bits = (r0, r1, L0..L5) = qubits 0..7;
// r0,r1 = in-register index j (4 complex amps/lane), L0..L5 = lane bits.
// ---------------------------------------------------------------------------

// in-register pair (a0 = bit 0, a1 = bit 1 of the gate's qubit)
__device__ __forceinline__ void cgate_pair(const float* __restrict__ u,
        float& r0, float& i0, float& r1, float& i1) {
    float nr0 = u[0]*r0 - u[1]*i0 + u[2]*r1 - u[3]*i1;
    float ni0 = u[0]*i0 + u[1]*r0 + u[2]*i1 + u[3]*r1;
    float nr1 = u[4]*r0 - u[5]*i0 + u[6]*r1 - u[7]*i1;
    float ni1 = u[4]*i0 + u[5]*r0 + u[6]*i1 + u[7]*r1;
    r0 = nr0; i0 = ni0; r1 = nr1; i1 = ni1;
}

// cross-lane via ds_bpermute (masks 4,8,16,32)
__device__ __forceinline__ void cgate_shfl(const float* __restrict__ u, int bit,
        int mask, float (&re)[4], float (&im)[4]) {
    float dr  = bit ? u[6] : u[0], di = bit ? u[7] : u[1];
    float orr = bit ? u[4] : u[2], oi = bit ? u[5] : u[3];
#pragma unroll
    for (int j = 0; j < 4; j++) {
        float pr = __shfl_xor(re[j], mask);
        float pi = __shfl_xor(im[j], mask);
        float nr = dr*re[j] - di*im[j] + orr*pr - oi*pi;
        float ni = dr*im[j] + di*re[j] + orr*pi + oi*pr;
        re[j] = nr; im[j] = ni;
    }
}

// cross-lane via DPP quad_perm (masks 1,2)
template <int CTRL>
__device__ __forceinline__ void cgate_dpp(const float* __restrict__ u, int bit,
        float (&re)[4], float (&im)[4]) {
    float dr  = bit ? u[6] : u[0], di = bit ? u[7] : u[1];
    float orr = bit ? u[4] : u[2], oi = bit ? u[5] : u[3];
#pragma unroll
    for (int j = 0; j < 4; j++) {
        float pr = dpp_xor<CTRL>(re[j]);
        float pi = dpp_xor<CTRL>(im[j]);
        float nr = dr*re[j] - di*im[j] + orr*pr - oi*pi;
        float ni = dr*im[j] + di*re[j] + orr*pi + oi*pr;
        re[j] = nr; im[j] = ni;
    }
}

__global__ __launch_bounds__(256) void qsim_kernel(
        const float* __restrict__ x, const float* __restrict__ proj_w,
        const float* __restrict__ gates, const float* __restrict__ out_w,
        const float* __restrict__ out_b, float* __restrict__ out) {
    int tid  = threadIdx.x;
    int lane = tid & 63;
    int b    = blockIdx.x * 4 + (tid >> 6); // grid exactly covers NBATCH

    // ---- encoding dots: d[q] = x[b]·proj_w[q] (float4 loads + DPP reduce) --
    const float4* xr4 = (const float4*)(x + (size_t)b * FEAT);
    float4 xa = xr4[lane], xb = xr4[lane + 64];
    float dq[8];
#pragma unroll
    for (int q = 0; q < 8; q++) {
        const float4* pw4 = (const float4*)(proj_w + q * FEAT);
        float4 wa = pw4[lane], wb = pw4[lane + 64];
        float acc = xa.x*wa.x + xa.y*wa.y + xa.z*wa.z + xa.w*wa.w
                  + xb.x*wb.x + xb.y*wb.y + xb.z*wb.z + xb.w*wb.w;
        dq[q] = wave_sum_bcast(acc);
    }
    // lane group g = lane>>3 computes sincos of half-angle for qubit g
    int qsel = lane >> 3;
    float a0 = (qsel & 4) ? dq[4] : dq[0];
    float a1 = (qsel & 4) ? dq[5] : dq[1];
    float a2 = (qsel & 4) ? dq[6] : dq[2];
    float a3 = (qsel & 4) ? dq[7] : dq[3];
    float b0 = (qsel & 2) ? a2 : a0;
    float b1 = (qsel & 2) ? a3 : a1;
    float dsel = (qsel & 1) ? b1 : b0;
    float th = fast_tanh(dsel) * 0.78539816339744830962f; // (pi/2)*tanh / 2
    float se = __sinf(th), ce = __cosf(th);
    float cq[8], sq[8];
#pragma unroll
    for (int q = 0; q < 8; q++) {
        cq[q] = bcastlane(ce, q * 8);
        sq[q] = bcastlane(se, q * 8);
    }

    // ---- encoding layer as product state: amp(i) = prod_q (bit? s_q : c_q) -
    float F = 1.f;
#pragma unroll
    for (int q = 2; q < 8; q++) {
        int bit = (lane >> (q - 2)) & 1;
        F *= bit ? sq[q] : cq[q];
    }
    float re[4], im[4];
    re[0] = F * cq[0] * cq[1];
    re[1] = F * sq[0] * cq[1];
    re[2] = F * cq[0] * sq[1];
    re[3] = F * sq[0] * sq[1];
    im[0] = im[1] = im[2] = im[3] = 0.f;

    // ---- variational layers ------------------------------------------------
#pragma unroll
    for (int l = 0; l < NDEPTH; l++) {
        const float* g = gates + l * NQ * 8;
        // q0 (reg bit 0): pairs (0,1),(2,3)
        cgate_pair(g, re[0], im[0], re[1], im[1]);
        cgate_pair(g, re[2], im[2], re[3], im[3]);
        // q1 (reg bit 1): pairs (0,2),(1,3)
        cgate_pair(g + 8,  re[0], im[0], re[2], im[2]);
        cgate_pair(g + 8,  re[1], im[1], re[3], im[3]);
        // q2,q3: DPP quad_perm xor1/xor2 (VALU, no DS)
        cgate_dpp<0xB1>(g + 16, lane & 1,        re, im);
        cgate_dpp<0x4E>(g + 24, (lane >> 1) & 1, re, im);
        // q4..q7: ds_bpermute xor 4,8,16,32
        cgate_shfl(g + 32, (lane >> 2) & 1, 4,  re, im);
        cgate_shfl(g + 40, (lane >> 3) & 1, 8,  re, im);
        cgate_shfl(g + 48, (lane >> 4) & 1, 16, re, im);
        cgate_shfl(g + 56, (lane >> 5) & 1, 32, re, im);

        // ---- CNOT ladder, composed ----------------------------------------
        // C(0,1): r1 ^= r0 -> swap regs 1,3 (local)
        { float t = re[1]; re[1] = re[3]; re[3] = t;
          t = im[1]; im[1] = im[3]; im[3] = t; }
        // C(1,2)..C(6,7) composed into one lane permutation per reg:
        // src_lane = (lane ^ ((lane<<1)&63)) ^ r1(dest reg bit1)
        int base  = lane ^ ((lane << 1) & 63);
        int base2 = base ^ 1;
        re[0] = __shfl(re[0], base);  im[0] = __shfl(im[0], base);
        re[1] = __shfl(re[1], base);  im[1] = __shfl(im[1], base);
        re[2] = __shfl(re[2], base2); im[2] = __shfl(im[2], base2);
        re[3] = __shfl(re[3], base2); im[3] = __shfl(im[3], base2);
        // C(7,0): r0 ^= L5 -> conditional in-lane swap (0,1),(2,3)
        int bit5 = (lane >> 5) & 1;
        {
            float t0 = bit5 ? re[1] : re[0], t1 = bit5 ? re[0] : re[1];
            float t2 = bit5 ? re[3] : re[2], t3 = bit5 ? re[2] : re[3];
            re[0] = t0; re[1] = t1; re[2] = t2; re[3] = t3;
            t0 = bit5 ? im[1] : im[0]; t1 = bit5 ? im[0] : im[1];
            t2 = bit5 ? im[3] : im[2]; t3 = bit5 ? im[2] : im[3];
            im[0] = t0; im[1] = t1; im[2] = t2; im[3] = t3;
        }
    }

    // ---- PauliZ expectations (DPP reductions) ------------------------------
    float p0 = re[0]*re[0] + im[0]*im[0];
    float p1 = re[1]*re[1] + im[1]*im[1];
    float p2 = re[2]*re[2] + im[2]*im[2];
    float p3 = re[3]*re[3] + im[3]*im[3];
    float pt = p0 + p1 + p2 + p3;
    float eq[8];
    eq[0] = wave_sum_bcast(p0 - p1 + p2 - p3); // sign by r0
    eq[1] = wave_sum_bcast(p0 + p1 - p2 - p3); // sign by r1
#pragma unroll
    for (int q = 2; q < 8; q++) {
        int bit = (lane >> (q - 2)) & 1;
        eq[q] = wave_sum_bcast(bit ? -pt : pt);
    }

    // ---- output head -------------------------------------------------------
    if (lane < NCLS) {
        const float* wrow = out_w + lane * NQ;
        float acc = out_b[lane];
#pragma unroll
        for (int q = 0; q < 8; q++) acc = fmaf(eq[q], wrow[q], acc);
        out[(size_t)b * NCLS + lane] = acc;
    }
}

extern "C" void kernel_launch(void* const* d_in, const int* in_sizes, int n_in,
                              void* d_out, int out_size, void* d_ws, size_t ws_size,
                              hipStream_t stream) {
    const float* x      = (const float*)d_in[0];
    const float* proj_w = (const float*)d_in[1];
    const float* qnn_w  = (const float*)d_in[2];
    const float* out_w  = (const float*)d_in[3];
    const float* out_b  = (const float*)d_in[4];
    float* out   = (float*)d_out;
    float* gates = (float*)d_ws; // 24 gates * 8 floats = 768 B

    gate_precompute<<<1, 64, 0, stream>>>(qnn_w, gates);
    qsim_kernel<<<NBATCH / 4, 256, 0, stream>>>(x, proj_w, gates, out_w, out_b, out);
}